// Round 13
// baseline (527.316 us; speedup 1.0000x reference)
//
#include <hip/hip_runtime.h>

namespace {
constexpr int kB  = 2;
constexpr int kNC = 4096;
constexpr int kNT = 1024;
constexpr int kDX = 64;
constexpr int kK  = 32;
constexpr int kNQ = kB * (kNC + kNT);            // 10240
constexpr int kQPB2 = kNC + kNT;                 // 5120 queries per batch
constexpr long long kE = (long long)kNQ * kK;    // 327680
constexpr int QPW  = 4;                          // queries per wave
constexpr int WAVES = 4;                         // waves per block
constexpr int QPB  = WAVES * QPW;                // 16 queries per block
constexpr int TILE = 64;                         // refs per LDS tile
constexpr int HALF = 2048;                       // refs per split-K block
constexpr int NGRP = kNQ / QPB;                  // 640 query groups
constexpr int GPB  = NGRP / kB;                  // 320 groups per batch
// inf stand-in: must stay finite after bf16 round-trip (FLT_MAX -> bf16 inf)
constexpr float kBigFinite = 1e30f;
// ---- ws layout (bytes) ----
constexpr size_t kOffRn    = 0;                       // f32 [8192]
constexpr size_t kOffPermR = 32768;                   // int [2][4096]
constexpr size_t kOffPrefR = 65536;                   // int [2][257]
constexpr size_t kOffCntR  = 67840;                   // int [2][256]
constexpr size_t kOffPrefQ = 69888;                   // int [2][257]
constexpr size_t kOffCntQ  = 72192;                   // int [2][256]
constexpr size_t kOffQperm = 74240;                   // int [2][5120]
constexpr size_t kOffKeys  = 115200;                  // u64 [kNQ][2][32]
constexpr size_t kWsNeed   = kOffKeys + (size_t)kNQ * 64 * 8;  // ~5.36MB
}

__device__ __forceinline__ int tbucket(float t) {
    int b = (int)(t * 256.0f);
    return b < 0 ? 0 : (b > 255 ? 255 : b);
}

__device__ __forceinline__ void resolve_q(int gid,
    const float* x_ctx, const float* s_ctx, const float* t_ctx,
    const float* x_test, const float* s_test, const float* t_test,
    int& b, const float*& qx, const float*& qs, const float*& qt)
{
    if (gid < kB * kNC) {
        b  = gid >> 12;
        qx = x_ctx + (size_t)gid * kDX;
        qs = s_ctx + (size_t)gid * 3;
        qt = t_ctx + gid;
    } else {
        const int g2 = gid - kB * kNC;
        b  = g2 >> 10;
        qx = x_test + (size_t)g2 * kDX;
        qs = s_test + (size_t)g2 * 3;
        qt = t_test + g2;
    }
}

// Exact online insert into wave-held sorted ascending top-32 (validated r4-r12).
__device__ __forceinline__ void insert_half(unsigned long long& listKey,
    unsigned long long keyQ, int lane, int base)
{
    const unsigned long long thr = __shfl(listKey, base + 31, 64);
    unsigned long long hb = __ballot(keyQ < thr);
    while (hb) {
        const int srcl = __ffsll((unsigned long long)hb) - 1;
        hb &= hb - 1;
        const unsigned long long K = __shfl(keyQ, srcl, 64);
        const unsigned long long lt = __ballot(listKey < K);
        const unsigned int half = base ? (unsigned int)(lt >> 32)
                                       : (unsigned int)lt;
        const int pos = __popc(half) + base;
        if (pos < base + 32) {
            const unsigned long long up = __shfl_up(listKey, 1, 64);
            if (lane >= base && lane < base + 32) {
                if (lane > pos)       listKey = up;
                else if (lane == pos) listKey = K;
            }
        }
    }
}

// ---- prep: rn[row] with the exact validated fmaf chain (validated r5-r12) ----
__global__ __launch_bounds__(256)
void prep_rn(const float* __restrict__ x, float* __restrict__ rn_ws)
{
    const int r = blockIdx.x * 256 + threadIdx.x;    // 0..8191
    const float4* xr = (const float4*)(x + (size_t)r * kDX);
    float rn = 0.f;
    #pragma unroll
    for (int j = 0; j < 16; ++j) {
        const float4 rv = xr[j];
        rn = fmaf(rv.x, rv.x, rn); rn = fmaf(rv.y, rv.y, rn);
        rn = fmaf(rv.z, rv.z, rn); rn = fmaf(rv.w, rv.w, rn);
    }
    rn_ws[r] = rn;
}

// ---- prep: zero histogram counters ----
__global__ __launch_bounds__(256)
void prep_zero(int* __restrict__ cntR, int* __restrict__ cntQ)
{
    const int i = blockIdx.x * 256 + threadIdx.x;    // grid 4 -> 1024
    if (i < 512) cntR[i] = 0;
    else         cntQ[i - 512] = 0;
}

// ---- prep: histogram refs (by rt) and queries (by qt) into 256 buckets ----
__global__ __launch_bounds__(256)
void prep_hist(const float* __restrict__ t_ctx, const float* __restrict__ t_test,
               int* __restrict__ cntR, int* __restrict__ cntQ)
{
    const int i = blockIdx.x * 256 + threadIdx.x;    // grid 72 -> 18432
    if (i < 8192) {
        const int b = i >> 12;
        atomicAdd(&cntR[b * 256 + tbucket(t_ctx[i])], 1);
    } else {
        const int gid = i - 8192;
        const int b = (gid < kB * kNC) ? (gid >> 12) : ((gid - kB * kNC) >> 10);
        const float qt = (gid < kB * kNC) ? t_ctx[gid] : t_test[gid - kB * kNC];
        atomicAdd(&cntQ[b * 256 + tbucket(qt)], 1);
    }
}

// ---- prep: exclusive prefix over 256 buckets; reset cnt to offsets ----
__global__ __launch_bounds__(256)
void prep_prefix(int* __restrict__ cntR, int* __restrict__ cntQ,
                 int* __restrict__ prefR, int* __restrict__ prefQ)
{
    __shared__ int sh[256];
    const int blk = blockIdx.x;          // 0,1: refs b; 2,3: queries b
    int* cnt  = (blk < 2) ? (cntR  + blk * 256) : (cntQ  + (blk - 2) * 256);
    int* pref = (blk < 2) ? (prefR + blk * 257) : (prefQ + (blk - 2) * 257);
    const int tid = threadIdx.x;
    sh[tid] = cnt[tid];
    __syncthreads();
    if (tid == 0) {
        int acc = 0;
        for (int i = 0; i < 256; ++i) { const int v = sh[i]; sh[i] = acc; acc += v; }
        pref[256] = acc;
    }
    __syncthreads();
    pref[tid] = sh[tid];
    cnt[tid]  = sh[tid];
}

// ---- prep: scatter refs/queries into bucket-sorted order ----
__global__ __launch_bounds__(256)
void prep_scatter(const float* __restrict__ t_ctx, const float* __restrict__ t_test,
                  int* __restrict__ cntR, int* __restrict__ cntQ,
                  int* __restrict__ permR, int* __restrict__ qperm)
{
    const int i = blockIdx.x * 256 + threadIdx.x;    // grid 72
    if (i < 8192) {
        const int b = i >> 12, rl = i & (kNC - 1);
        const int pos = atomicAdd(&cntR[b * 256 + tbucket(t_ctx[i])], 1);
        permR[b * kNC + pos] = rl;
    } else {
        const int gid = i - 8192;
        const int b = (gid < kB * kNC) ? (gid >> 12) : ((gid - kB * kNC) >> 10);
        const float qt = (gid < kB * kNC) ? t_ctx[gid] : t_test[gid - kB * kNC];
        const int pos = atomicAdd(&cntQ[b * 256 + tbucket(qt)], 1);
        qperm[b * kQPB2 + pos] = gid;
    }
}

// ---- main: causal-pruned split-K scan over rt-sorted refs ----
__global__ __launch_bounds__(256, 4)
void knn_v7_part(const float* __restrict__ x_ctx, const float* __restrict__ s_ctx,
                 const float* __restrict__ t_ctx, const unsigned char* __restrict__ mask_ctx,
                 const float* __restrict__ x_test, const float* __restrict__ s_test,
                 const float* __restrict__ t_test, const float* __restrict__ rn_ws,
                 const int* __restrict__ permR, const int* __restrict__ prefR,
                 const int* __restrict__ qperm, unsigned long long* __restrict__ keys)
{
    __shared__ float4 xt[2][TILE * 16];   // 2 x 16KB double-buffered ref tiles
    __shared__ int wred[WAVES];

    const int tid  = threadIdx.x;
    const int lane = tid & 63;
    const int w    = __builtin_amdgcn_readfirstlane(tid >> 6);
    const int blk  = blockIdx.x;                 // 1280
    const int gidx = (NGRP - 1) - (blk >> 1);    // heavy (high-qt) groups first
    const int h    = blk & 1;                    // ref half (of permuted order)
    const int b    = (gidx >= GPB) ? 1 : 0;
    const int gg   = gidx - b * GPB;             // group within batch

    const int* qpm = qperm + b * kQPB2 + gg * QPB;
    int gid_q[QPW];
    #pragma unroll
    for (int q = 0; q < QPW; ++q) gid_q[q] = qpm[w * QPW + q];

    const float4* xb4 = (const float4*)x_ctx + (size_t)b * kNC * (kDX / 4);
    const float*  rsp = s_ctx + (size_t)b * kNC * 3;
    const float*  rtp = t_ctx + (size_t)b * kNC;
    const float*  rnp = rn_ws + (size_t)b * kNC;
    const unsigned char* mp = mask_ctx + (size_t)b * kNC;
    const int* pR = permR + b * kNC;
    const int* pf = prefR + b * 257;

    // ---- per-wave query setup (4 queries; pointers wave-uniform) ----
    const float* qxp[QPW];
    float qs0[QPW], qs1[QPW], qs2[QPW], qsn[QPW], qtv[QPW], qn[QPW];
    #pragma unroll
    for (int q = 0; q < QPW; ++q) {
        int bb; const float *qx, *qs, *qt;
        resolve_q(gid_q[q], x_ctx, s_ctx, t_ctx, x_test, s_test, t_test,
                  bb, qx, qs, qt);
        qxp[q] = qx;
        qs0[q] = qs[0]; qs1[q] = qs[1]; qs2[q] = qs[2]; qtv[q] = qt[0];
        qsn[q] = qs0[q]*qs0[q] + qs1[q]*qs1[q] + qs2[q]*qs2[q];
        const float ql = qx[lane];
        float s = ql * ql;
        #pragma unroll
        for (int off = 32; off > 0; off >>= 1) s += __shfl_xor(s, off, 64);
        qn[q] = s;
    }

    // ---- causal scan bound, block-uniform (barriers inside loop!) ----
    // refs in permuted order: buckets <= qb cover all rt <= qt. If fewer than
    // K refs are *guaranteed* causal (prefix[qb] < K), the inf-fill (smallest
    // original idx among non-causal) needs the FULL range -> scan everything.
    int vmax = 0;
    #pragma unroll
    for (int q = 0; q < QPW; ++q) {
        const int qb = tbucket(qtv[q]);
        int bound = pf[qb + 1];
        if (pf[qb] < kK) bound = kNC;
        vmax = bound > vmax ? bound : vmax;
    }
    if (lane == 0) wred[w] = vmax;
    __syncthreads();
    int bmax = wred[0];
    #pragma unroll
    for (int i = 1; i < WAVES; ++i) bmax = wred[i] > bmax ? wred[i] : bmax;

    const int lo = h * HALF;
    const int hi = bmax < lo + HALF ? bmax : lo + HALF;
    const int ntile = (hi > lo) ? ((hi - lo + TILE - 1) >> 6) : 0;

    // staging geometry: 4 float4 per thread per tile, XOR-swizzled LDS dest
    int rrow[4], rcol[4], ssz[4];
    #pragma unroll
    for (int i = 0; i < 4; ++i) {
        const int n = tid + 256 * i;
        rrow[i] = n >> 4; rcol[i] = n & 15;
        ssz[i]  = (rrow[i] << 4) | (rcol[i] ^ (rrow[i] & 7));
    }
    if (ntile > 0) {
        #pragma unroll
        for (int i = 0; i < 4; ++i) {
            const int o = pR[lo + rrow[i]];
            xt[0][ssz[i]] = xb4[(size_t)o * 16 + rcol[i]];
        }
    }
    __syncthreads();

    const int lbase = lane << 4, lsw = lane & 7;
    const float INF = __builtin_inff();
    unsigned long long lst01 = ~0ull, lst23 = ~0ull;

    for (int t = 0; t < ntile; ++t) {
        const bool pre = (t + 1 < ntile);
        float4 p4[4];
        if (pre) {
            #pragma unroll
            for (int i = 0; i < 4; ++i) {
                const int o = pR[lo + (t + 1) * TILE + rrow[i]];
                p4[i] = xb4[(size_t)o * 16 + rcol[i]];
            }
        }
        // this lane's ref: permuted position -> original index (key idx!)
        const int o = pR[lo + t * TILE + lane];
        const float rn  = rnp[o];
        const float rs0 = rsp[o*3+0], rs1 = rsp[o*3+1], rs2 = rsp[o*3+2];
        const float rtv = rtp[o];
        const bool  m   = (mp[o] != 0);

        const float4* buf = xt[t & 1];
        float dot[QPW] = {0.f, 0.f, 0.f, 0.f};
        #pragma unroll
        for (int j = 0; j < 16; ++j) {
            const float4 rv = buf[lbase | (j ^ lsw)];
            #pragma unroll
            for (int q = 0; q < QPW; ++q) {
                const float4 qv = ((const float4*)qxp[q])[j];   // s_load (uniform)
                dot[q] = fmaf(qv.x, rv.x, dot[q]);
                dot[q] = fmaf(qv.y, rv.y, dot[q]);
                dot[q] = fmaf(qv.z, rv.z, dot[q]);
                dot[q] = fmaf(qv.w, rv.w, dot[q]);
            }
        }

        const float rsn = rs0*rs0 + rs1*rs1 + rs2*rs2;
        #pragma unroll
        for (int q = 0; q < QPW; ++q) {
            float d_x = qn[q] + rn - 2.0f * dot[q];
            const float sdot = qs0[q]*rs0 + qs1[q]*rs1 + qs2[q]*rs2;
            float d_s = qsn[q] + rsn - 2.0f * sdot;
            float d_t = rtv - qtv[q];
            if (!m) { d_x = INF; d_s = INF; d_t = INF; }
            if (!(d_t <= 0.f)) d_t = INF;
            const float v = d_x*d_x + d_s*d_s + d_t*d_t;
            const unsigned long long key =
                ((unsigned long long)__float_as_uint(v) << 32) | (unsigned)o;
            if (q < 2) insert_half(lst01, key, lane, (q & 1) * 32);
            else       insert_half(lst23, key, lane, (q & 1) * 32);
        }

        if (pre) {
            float4* nb = xt[(t + 1) & 1];
            #pragma unroll
            for (int i = 0; i < 4; ++i) nb[ssz[i]] = p4[i];
        }
        __syncthreads();
    }

    // ---- write per-half sorted key lists: keys[gid][h][slot] ----
    #pragma unroll
    for (int p = 0; p < 2; ++p) {
        const unsigned long long key = p ? lst23 : lst01;
        const int gsel = (lane < 32) ? gid_q[2*p] : gid_q[2*p+1];
        keys[((size_t)gsel * 2 + h) * 32 + (lane & 31)] = key;
    }
}

// ---- merge two sorted 32-lists per query + validated emit (validated r7/r12) ----
__global__ __launch_bounds__(256)
void knn_v5_merge(const float* __restrict__ x_ctx, const float* __restrict__ s_ctx,
                  const float* __restrict__ t_ctx, const unsigned char* __restrict__ mask_ctx,
                  const float* __restrict__ x_test, const float* __restrict__ s_test,
                  const float* __restrict__ t_test,
                  const unsigned long long* __restrict__ keys,
                  float* __restrict__ out)
{
    __shared__ unsigned long long kbuf[WAVES][64];
    __shared__ unsigned long long merged[WAVES][32];

    const int tid  = threadIdx.x;
    const int lane = tid & 63;
    const int w    = tid >> 6;
    const int qid  = blockIdx.x * WAVES + w;

    int b; const float *qx, *qs, *qt;
    resolve_q(qid, x_ctx, s_ctx, t_ctx, x_test, s_test, t_test, b, qx, qs, qt);
    const float qs0_ = qs[0], qs1_ = qs[1], qs2_ = qs[2], qtv_ = qt[0];
    const float qsn_ = qs0_*qs0_ + qs1_*qs1_ + qs2_*qs2_;
    const float ql = qx[lane];
    float qn_ = ql * ql;
    #pragma unroll
    for (int off = 32; off > 0; off >>= 1) qn_ += __shfl_xor(qn_, off, 64);

    const unsigned long long mykey = keys[(size_t)qid * 64 + lane];
    kbuf[w][lane] = mykey;
    __syncthreads();

    int cnt = 0;
    const int ob = (lane < 32) ? 32 : 0;
    #pragma unroll
    for (int j = 0; j < 32; ++j) cnt += (kbuf[w][ob + j] < mykey) ? 1 : 0;
    const int pos = (lane & 31) + cnt;
    if (pos < 32) merged[w][pos] = mykey;
    __syncthreads();

    if (lane < kK) {
        const unsigned long long key = merged[w][lane];
        const int rsel = (int)(key & 0xFFFFFFFFull);

        const float*  rsp = s_ctx + (size_t)b * kNC * 3;
        const float*  rtp = t_ctx + (size_t)b * kNC;
        const unsigned char* mp = mask_ctx + (size_t)b * kNC;

        const float4* xr = (const float4*)(x_ctx + ((size_t)b * kNC + rsel) * kDX);
        const float4* qr = (const float4*)qx;
        float dot = 0.f, rn2 = 0.f;
        #pragma unroll
        for (int j = 0; j < 16; ++j) {
            const float4 rv = xr[j];
            const float4 qv = qr[j];
            rn2 = fmaf(rv.x, rv.x, rn2); rn2 = fmaf(rv.y, rv.y, rn2);
            rn2 = fmaf(rv.z, rv.z, rn2); rn2 = fmaf(rv.w, rv.w, rn2);
            dot = fmaf(qv.x, rv.x, dot); dot = fmaf(qv.y, rv.y, dot);
            dot = fmaf(qv.z, rv.z, dot); dot = fmaf(qv.w, rv.w, dot);
        }
        float d_x = qn_ + rn2 - 2.0f * dot;
        const float rs0 = rsp[rsel*3+0], rs1 = rsp[rsel*3+1], rs2 = rsp[rsel*3+2];
        const float rsn = rs0*rs0 + rs1*rs1 + rs2*rs2;
        const float sdot = qs0_*rs0 + qs1_*rs1 + qs2_*rs2;
        float d_s = qsn_ + rsn - 2.0f * sdot;
        const float dt_raw = rtp[rsel] - qtv_;
        const bool  m = (mp[rsel] != 0);
        const bool  causal = m && (dt_raw <= 0.f);

        const float em = causal ? 1.0f : 0.0f;
        const float d_x_out = m ? d_x : kBigFinite;
        const float d_s_out = m ? d_s : kBigFinite;
        const float d_t_out = causal ? dt_raw : kBigFinite;

        const size_t e = (size_t)qid * kK + (size_t)lane;
        out[e]                = (float)(rsel + b * kNC);
        out[(size_t)kE   + e] = (float)qid;
        out[(size_t)kE*2 + e] = d_x_out;
        out[(size_t)kE*3 + e] = d_s_out;
        out[(size_t)kE*4 + e] = d_t_out;
        out[(size_t)kE*5 + e] = em;
    }
}

// ================= fallback: validated round-6 kernel (v4) =================
__global__ __launch_bounds__(256, 4)
void knn_v4(const float* __restrict__ x_ctx, const float* __restrict__ s_ctx,
            const float* __restrict__ t_ctx, const unsigned char* __restrict__ mask_ctx,
            const float* __restrict__ x_test, const float* __restrict__ s_test,
            const float* __restrict__ t_test, float* __restrict__ out)
{
    __shared__ float4 xt[2][TILE * 16];
    const int tid  = threadIdx.x;
    const int lane = tid & 63;
    const int w    = __builtin_amdgcn_readfirstlane(tid >> 6);
    const int qbase = blockIdx.x * QPB;
    const int gid0  = qbase + w * QPW;
    int b;
    { int b_; const float *a, *c, *d;
      resolve_q(qbase, x_ctx, s_ctx, t_ctx, x_test, s_test, t_test, b_, a, c, d);
      b = b_; }
    const float4* xb4 = (const float4*)x_ctx + (size_t)b * kNC * (kDX / 4);
    const float*  rsp = s_ctx + (size_t)b * kNC * 3;
    const float*  rtp = t_ctx + (size_t)b * kNC;
    const unsigned char* mp = mask_ctx + (size_t)b * kNC;
    const float* qxp[QPW];
    float qs0[QPW], qs1[QPW], qs2[QPW], qsn[QPW], qtv[QPW], qn[QPW];
    #pragma unroll
    for (int q = 0; q < QPW; ++q) {
        int bb; const float *qx, *qs, *qt;
        resolve_q(gid0 + q, x_ctx, s_ctx, t_ctx, x_test, s_test, t_test, bb, qx, qs, qt);
        qxp[q] = qx;
        qs0[q] = qs[0]; qs1[q] = qs[1]; qs2[q] = qs[2]; qtv[q] = qt[0];
        qsn[q] = qs0[q]*qs0[q] + qs1[q]*qs1[q] + qs2[q]*qs2[q];
        const float ql = qx[lane];
        float s = ql * ql;
        #pragma unroll
        for (int off = 32; off > 0; off >>= 1) s += __shfl_xor(s, off, 64);
        qn[q] = s;
    }
    int sg[4], ss[4];
    #pragma unroll
    for (int i = 0; i < 4; ++i) {
        const int n = tid + 256 * i;
        const int r = n >> 4, j = n & 15;
        sg[i] = n; ss[i] = (r << 4) | (j ^ (r & 7));
    }
    #pragma unroll
    for (int i = 0; i < 4; ++i) xt[0][ss[i]] = xb4[sg[i]];
    __syncthreads();
    const int lbase = lane << 4, lsw = lane & 7;
    const float INF = __builtin_inff();
    unsigned long long lst01 = ~0ull, lst23 = ~0ull;
    for (int t = 0; t < kNC / TILE; ++t) {
        float4 p0, p1, p2, p3;
        const bool pre = (t + 1 < kNC / TILE);
        if (pre) {
            const size_t nb = (size_t)(t + 1) * 1024;
            p0 = xb4[nb + sg[0]]; p1 = xb4[nb + sg[1]];
            p2 = xb4[nb + sg[2]]; p3 = xb4[nb + sg[3]];
        }
        const float4* buf = xt[t & 1];
        float dot[QPW] = {0.f, 0.f, 0.f, 0.f};
        float rn = 0.f;
        #pragma unroll
        for (int j = 0; j < 16; ++j) {
            const float4 rv = buf[lbase | (j ^ lsw)];
            rn = fmaf(rv.x, rv.x, rn); rn = fmaf(rv.y, rv.y, rn);
            rn = fmaf(rv.z, rv.z, rn); rn = fmaf(rv.w, rv.w, rn);
            #pragma unroll
            for (int q = 0; q < QPW; ++q) {
                const float4 qv = ((const float4*)qxp[q])[j];
                dot[q] = fmaf(qv.x, rv.x, dot[q]);
                dot[q] = fmaf(qv.y, rv.y, dot[q]);
                dot[q] = fmaf(qv.z, rv.z, dot[q]);
                dot[q] = fmaf(qv.w, rv.w, dot[q]);
            }
        }
        const int r = t * TILE + lane;
        const float rs0 = rsp[r*3+0], rs1 = rsp[r*3+1], rs2 = rsp[r*3+2];
        const float rtv = rtp[r];
        const bool  m   = (mp[r] != 0);
        const float rsn = rs0*rs0 + rs1*rs1 + rs2*rs2;
        #pragma unroll
        for (int q = 0; q < QPW; ++q) {
            float d_x = qn[q] + rn - 2.0f * dot[q];
            const float sdot = qs0[q]*rs0 + qs1[q]*rs1 + qs2[q]*rs2;
            float d_s = qsn[q] + rsn - 2.0f * sdot;
            float d_t = rtv - qtv[q];
            if (!m) { d_x = INF; d_s = INF; d_t = INF; }
            if (!(d_t <= 0.f)) d_t = INF;
            const float v = d_x*d_x + d_s*d_s + d_t*d_t;
            const unsigned long long key =
                ((unsigned long long)__float_as_uint(v) << 32) | (unsigned)r;
            if (q < 2) insert_half(lst01, key, lane, (q & 1) * 32);
            else       insert_half(lst23, key, lane, (q & 1) * 32);
        }
        if (pre) {
            float4* nbuf = xt[(t + 1) & 1];
            nbuf[ss[0]] = p0; nbuf[ss[1]] = p1;
            nbuf[ss[2]] = p2; nbuf[ss[3]] = p3;
        }
        __syncthreads();
    }
    #pragma unroll
    for (int p = 0; p < 2; ++p) {
        const unsigned long long myl = p ? lst23 : lst01;
        const int qidx = 2 * p + (lane >> 5);
        const int rsel = (int)(myl & 0xFFFFFFFFull);
        const int gid  = gid0 + qidx;
        const float* qx  = (lane < 32) ? qxp[2*p] : qxp[2*p+1];
        const float qn_  = (lane < 32) ? qn [2*p] : qn [2*p+1];
        const float qs0_ = (lane < 32) ? qs0[2*p] : qs0[2*p+1];
        const float qs1_ = (lane < 32) ? qs1[2*p] : qs1[2*p+1];
        const float qs2_ = (lane < 32) ? qs2[2*p] : qs2[2*p+1];
        const float qsn_ = (lane < 32) ? qsn[2*p] : qsn[2*p+1];
        const float qtv_ = (lane < 32) ? qtv[2*p] : qtv[2*p+1];
        const float4* xr = (const float4*)(x_ctx + ((size_t)b * kNC + rsel) * kDX);
        const float4* qr = (const float4*)qx;
        float dot = 0.f, rn2 = 0.f;
        #pragma unroll
        for (int j = 0; j < 16; ++j) {
            const float4 rv = xr[j];
            const float4 qv = qr[j];
            rn2 = fmaf(rv.x, rv.x, rn2); rn2 = fmaf(rv.y, rv.y, rn2);
            rn2 = fmaf(rv.z, rv.z, rn2); rn2 = fmaf(rv.w, rv.w, rn2);
            dot = fmaf(qv.x, rv.x, dot); dot = fmaf(qv.y, rv.y, dot);
            dot = fmaf(qv.z, rv.z, dot); dot = fmaf(qv.w, rv.w, dot);
        }
        float d_x = qn_ + rn2 - 2.0f * dot;
        const float rs0 = rsp[rsel*3+0], rs1 = rsp[rsel*3+1], rs2 = rsp[rsel*3+2];
        const float rsn = rs0*rs0 + rs1*rs1 + rs2*rs2;
        const float sdot = qs0_*rs0 + qs1_*rs1 + qs2_*rs2;
        float d_s = qsn_ + rsn - 2.0f * sdot;
        const float dt_raw = rtp[rsel] - qtv_;
        const bool  m = (mp[rsel] != 0);
        const bool  causal = m && (dt_raw <= 0.f);
        const float em = causal ? 1.0f : 0.0f;
        const size_t e = (size_t)gid * kK + (size_t)(lane & 31);
        out[e]                = (float)(rsel + b * kNC);
        out[(size_t)kE   + e] = (float)gid;
        out[(size_t)kE*2 + e] = m ? d_x : kBigFinite;
        out[(size_t)kE*3 + e] = m ? d_s : kBigFinite;
        out[(size_t)kE*4 + e] = causal ? dt_raw : kBigFinite;
        out[(size_t)kE*5 + e] = em;
    }
}

extern "C" void kernel_launch(void* const* d_in, const int* in_sizes, int n_in,
                              void* d_out, int out_size, void* d_ws, size_t ws_size,
                              hipStream_t stream) {
    (void)in_sizes; (void)n_in; (void)out_size;
    const float* x_ctx = (const float*)d_in[0];
    const float* s_ctx = (const float*)d_in[1];
    const float* t_ctx = (const float*)d_in[2];
    const unsigned char* mask_ctx = (const unsigned char*)d_in[3];
    const float* x_test = (const float*)d_in[4];
    const float* s_test = (const float*)d_in[5];
    const float* t_test = (const float*)d_in[6];

    if (ws_size >= kWsNeed) {
        char* ws = (char*)d_ws;
        float* rn_ws = (float*)(ws + kOffRn);
        int*   permR = (int*)(ws + kOffPermR);
        int*   prefR = (int*)(ws + kOffPrefR);
        int*   cntR  = (int*)(ws + kOffCntR);
        int*   prefQ = (int*)(ws + kOffPrefQ);
        int*   cntQ  = (int*)(ws + kOffCntQ);
        int*   qperm = (int*)(ws + kOffQperm);
        unsigned long long* keys = (unsigned long long*)(ws + kOffKeys);

        prep_zero   <<<dim3(4),  dim3(256), 0, stream>>>(cntR, cntQ);
        prep_rn     <<<dim3(32), dim3(256), 0, stream>>>(x_ctx, rn_ws);
        prep_hist   <<<dim3(72), dim3(256), 0, stream>>>(t_ctx, t_test, cntR, cntQ);
        prep_prefix <<<dim3(4),  dim3(256), 0, stream>>>(cntR, cntQ, prefR, prefQ);
        prep_scatter<<<dim3(72), dim3(256), 0, stream>>>(t_ctx, t_test, cntR, cntQ,
                                                         permR, qperm);
        knn_v7_part <<<dim3(2 * NGRP), dim3(256), 0, stream>>>(
            x_ctx, s_ctx, t_ctx, mask_ctx, x_test, s_test, t_test,
            rn_ws, permR, prefR, qperm, keys);
        knn_v5_merge<<<dim3(kNQ / WAVES), dim3(256), 0, stream>>>(
            x_ctx, s_ctx, t_ctx, mask_ctx, x_test, s_test, t_test, keys,
            (float*)d_out);
    } else {
        knn_v4<<<dim3(kNQ / QPB), dim3(256), 0, stream>>>(
            x_ctx, s_ctx, t_ctx, mask_ctx, x_test, s_test, t_test, (float*)d_out);
    }
}

// Round 14
// 425.806 us; speedup vs baseline: 1.2384x; 1.2384x over previous
//
#include <hip/hip_runtime.h>

namespace {
constexpr int kB  = 2;
constexpr int kNC = 4096;
constexpr int kNT = 1024;
constexpr int kDX = 64;
constexpr int kK  = 32;
constexpr int kNQ = kB * (kNC + kNT);            // 10240
constexpr int kQPB2 = kNC + kNT;                 // 5120 queries per batch
constexpr long long kE = (long long)kNQ * kK;    // 327680
constexpr int QPW  = 4;                          // queries per wave
constexpr int WAVES = 4;                         // waves per block
constexpr int QPB  = WAVES * QPW;                // 16 queries per block
constexpr int TILE = 64;                         // refs per LDS tile
constexpr int HALF = 2048;                       // refs per split-K block
constexpr int NGRP = kNQ / QPB;                  // 640 query groups
constexpr int GPB  = NGRP / kB;                  // 320 groups per batch
// inf stand-in: must stay finite after bf16 round-trip (FLT_MAX -> bf16 inf)
constexpr float kBigFinite = 1e30f;
// ---- ws layout (bytes) ----
constexpr size_t kOffRn    = 0;                       // f32 [8192]
constexpr size_t kOffPermR = 32768;                   // int [2][4096]
constexpr size_t kOffPrefR = 65536;                   // int [2][257]
constexpr size_t kOffCntR  = 67840;                   // int [2][256]
constexpr size_t kOffPrefQ = 69888;                   // int [2][257]
constexpr size_t kOffCntQ  = 72192;                   // int [2][256]
constexpr size_t kOffQperm = 74240;                   // int [2][5120]
constexpr size_t kOffKeys  = 115200;                  // u64 [kNQ][2][32]
constexpr size_t kOffXp    = 5358080;                 // f32 [2][4096][64] permuted x
constexpr size_t kOffMs    = 13746688;                // f32x4 [2][4096] (rs0,rs1,rs2,rt)
constexpr size_t kOffMr    = 13877760;                // int2 [2][4096]  (rn_bits, orig_idx)
constexpr size_t kWsNeed   = kOffMr + (size_t)kB * kNC * 8;  // ~13.94MB
}

__device__ __forceinline__ int tbucket(float t) {
    int b = (int)(t * 256.0f);
    return b < 0 ? 0 : (b > 255 ? 255 : b);
}

__device__ __forceinline__ void resolve_q(int gid,
    const float* x_ctx, const float* s_ctx, const float* t_ctx,
    const float* x_test, const float* s_test, const float* t_test,
    int& b, const float*& qx, const float*& qs, const float*& qt)
{
    if (gid < kB * kNC) {
        b  = gid >> 12;
        qx = x_ctx + (size_t)gid * kDX;
        qs = s_ctx + (size_t)gid * 3;
        qt = t_ctx + gid;
    } else {
        const int g2 = gid - kB * kNC;
        b  = g2 >> 10;
        qx = x_test + (size_t)g2 * kDX;
        qs = s_test + (size_t)g2 * 3;
        qt = t_test + g2;
    }
}

// Exact online insert into wave-held sorted ascending top-32 (validated r4-r13).
__device__ __forceinline__ void insert_half(unsigned long long& listKey,
    unsigned long long keyQ, int lane, int base)
{
    const unsigned long long thr = __shfl(listKey, base + 31, 64);
    unsigned long long hb = __ballot(keyQ < thr);
    while (hb) {
        const int srcl = __ffsll((unsigned long long)hb) - 1;
        hb &= hb - 1;
        const unsigned long long K = __shfl(keyQ, srcl, 64);
        const unsigned long long lt = __ballot(listKey < K);
        const unsigned int half = base ? (unsigned int)(lt >> 32)
                                       : (unsigned int)lt;
        const int pos = __popc(half) + base;
        if (pos < base + 32) {
            const unsigned long long up = __shfl_up(listKey, 1, 64);
            if (lane >= base && lane < base + 32) {
                if (lane > pos)       listKey = up;
                else if (lane == pos) listKey = K;
            }
        }
    }
}

// ---- prep: rn[row] with the exact validated fmaf chain (validated r5-r13) ----
__global__ __launch_bounds__(256)
void prep_rn(const float* __restrict__ x, float* __restrict__ rn_ws)
{
    const int r = blockIdx.x * 256 + threadIdx.x;    // 0..8191
    const float4* xr = (const float4*)(x + (size_t)r * kDX);
    float rn = 0.f;
    #pragma unroll
    for (int j = 0; j < 16; ++j) {
        const float4 rv = xr[j];
        rn = fmaf(rv.x, rv.x, rn); rn = fmaf(rv.y, rv.y, rn);
        rn = fmaf(rv.z, rv.z, rn); rn = fmaf(rv.w, rv.w, rn);
    }
    rn_ws[r] = rn;
}

// ---- prep: zero histogram counters ----
__global__ __launch_bounds__(256)
void prep_zero(int* __restrict__ cntR, int* __restrict__ cntQ)
{
    const int i = blockIdx.x * 256 + threadIdx.x;
    if (i < 512) cntR[i] = 0;
    else         cntQ[i - 512] = 0;
}

// ---- prep: histogram refs (by rt) and queries (by qt) into 256 buckets ----
__global__ __launch_bounds__(256)
void prep_hist(const float* __restrict__ t_ctx, const float* __restrict__ t_test,
               int* __restrict__ cntR, int* __restrict__ cntQ)
{
    const int i = blockIdx.x * 256 + threadIdx.x;    // grid 72 -> 18432
    if (i < 8192) {
        const int b = i >> 12;
        atomicAdd(&cntR[b * 256 + tbucket(t_ctx[i])], 1);
    } else {
        const int gid = i - 8192;
        const int b = (gid < kB * kNC) ? (gid >> 12) : ((gid - kB * kNC) >> 10);
        const float qt = (gid < kB * kNC) ? t_ctx[gid] : t_test[gid - kB * kNC];
        atomicAdd(&cntQ[b * 256 + tbucket(qt)], 1);
    }
}

// ---- prep: exclusive prefix over 256 buckets; reset cnt to offsets ----
__global__ __launch_bounds__(256)
void prep_prefix(int* __restrict__ cntR, int* __restrict__ cntQ,
                 int* __restrict__ prefR, int* __restrict__ prefQ)
{
    __shared__ int sh[256];
    const int blk = blockIdx.x;          // 0,1: refs b; 2,3: queries b
    int* cnt  = (blk < 2) ? (cntR  + blk * 256) : (cntQ  + (blk - 2) * 256);
    int* pref = (blk < 2) ? (prefR + blk * 257) : (prefQ + (blk - 2) * 257);
    const int tid = threadIdx.x;
    sh[tid] = cnt[tid];
    __syncthreads();
    if (tid == 0) {
        int acc = 0;
        for (int i = 0; i < 256; ++i) { const int v = sh[i]; sh[i] = acc; acc += v; }
        pref[256] = acc;
    }
    __syncthreads();
    pref[tid] = sh[tid];
    cnt[tid]  = sh[tid];
}

// ---- prep: scatter refs/queries into bucket-sorted order ----
__global__ __launch_bounds__(256)
void prep_scatter(const float* __restrict__ t_ctx, const float* __restrict__ t_test,
                  int* __restrict__ cntR, int* __restrict__ cntQ,
                  int* __restrict__ permR, int* __restrict__ qperm)
{
    const int i = blockIdx.x * 256 + threadIdx.x;    // grid 72
    if (i < 8192) {
        const int b = i >> 12, rl = i & (kNC - 1);
        const int pos = atomicAdd(&cntR[b * 256 + tbucket(t_ctx[i])], 1);
        permR[b * kNC + pos] = rl;
    } else {
        const int gid = i - 8192;
        const int b = (gid < kB * kNC) ? (gid >> 12) : ((gid - kB * kNC) >> 10);
        const float qt = (gid < kB * kNC) ? t_ctx[gid] : t_test[gid - kB * kNC];
        const int pos = atomicAdd(&cntQ[b * 256 + tbucket(qt)], 1);
        qperm[b * kQPB2 + pos] = gid;
    }
}

// ---- prep: physically permute x panel + metadata into rt-sorted order ----
// Kills the hot-loop gather that sank v7 (505us, VALUBusy 27%).
__global__ __launch_bounds__(256)
void prep_permute(const float* __restrict__ x_ctx, const float* __restrict__ s_ctx,
                  const float* __restrict__ t_ctx, const unsigned char* __restrict__ mask_ctx,
                  const float* __restrict__ rn_ws, const int* __restrict__ permR,
                  float4* __restrict__ xp4, float4* __restrict__ msrt,
                  int2* __restrict__ mrn)
{
    const int n   = blockIdx.x * 256 + threadIdx.x;  // grid 512 -> 131072 float4
    const int b   = n >> 16;                          // 65536 float4 per batch
    const int rem = n & 65535;
    const int pos = rem >> 4, col = rem & 15;
    const int o   = permR[b * kNC + pos];
    xp4[n] = ((const float4*)x_ctx)[(size_t)b * kNC * 16 + (size_t)o * 16 + col];
    if (col == 0) {
        const float* rs = s_ctx + ((size_t)b * kNC + o) * 3;
        const float rtv = t_ctx[b * kNC + o];
        msrt[b * kNC + pos] = make_float4(rs[0], rs[1], rs[2], rtv);
        // mask folding: poison rn to +inf when masked-out -> v = +inf exactly
        // (same key bits as the validated d_x=d_s=d_t=INF path)
        const bool m = (mask_ctx[b * kNC + o] != 0);
        const float rn = rn_ws[b * kNC + o];
        mrn[b * kNC + pos] = make_int2(
            m ? __float_as_int(rn) : __float_as_int(__builtin_inff()), o);
    }
}

// ---- main: causal-pruned split-K scan over PHYSICALLY rt-sorted refs ----
__global__ __launch_bounds__(256, 4)
void knn_v8_part(const float* __restrict__ x_ctx, const float* __restrict__ s_ctx,
                 const float* __restrict__ t_ctx,
                 const float* __restrict__ x_test, const float* __restrict__ s_test,
                 const float* __restrict__ t_test,
                 const float4* __restrict__ xp4g, const float4* __restrict__ msrtg,
                 const int2* __restrict__ mrng,
                 const int* __restrict__ prefR, const int* __restrict__ qperm,
                 unsigned long long* __restrict__ keys)
{
    __shared__ float4 xt[2][TILE * 16];   // 2 x 16KB double-buffered ref tiles
    __shared__ int wred[WAVES];

    const int tid  = threadIdx.x;
    const int lane = tid & 63;
    const int w    = __builtin_amdgcn_readfirstlane(tid >> 6);
    const int blk  = blockIdx.x;                 // 1280
    const int gidx = (NGRP - 1) - (blk >> 1);    // heavy (high-qt) groups first
    const int h    = blk & 1;                    // ref half (of permuted order)
    const int b    = (gidx >= GPB) ? 1 : 0;
    const int gg   = gidx - b * GPB;             // group within batch

    const int* qpm = qperm + b * kQPB2 + gg * QPB;
    int gid_q[QPW];
    #pragma unroll
    for (int q = 0; q < QPW; ++q) gid_q[q] = qpm[w * QPW + q];

    const float4* xp4  = xp4g  + (size_t)b * kNC * 16;
    const float4* msrt = msrtg + (size_t)b * kNC;
    const int2*   mrn  = mrng  + (size_t)b * kNC;
    const int*    pf   = prefR + b * 257;

    // ---- per-wave query setup (4 queries; pointers wave-uniform) ----
    const float* qxp[QPW];
    float qs0[QPW], qs1[QPW], qs2[QPW], qsn[QPW], qtv[QPW], qn[QPW];
    #pragma unroll
    for (int q = 0; q < QPW; ++q) {
        int bb; const float *qx, *qs, *qt;
        resolve_q(gid_q[q], x_ctx, s_ctx, t_ctx, x_test, s_test, t_test,
                  bb, qx, qs, qt);
        qxp[q] = qx;
        qs0[q] = qs[0]; qs1[q] = qs[1]; qs2[q] = qs[2]; qtv[q] = qt[0];
        qsn[q] = qs0[q]*qs0[q] + qs1[q]*qs1[q] + qs2[q]*qs2[q];
        const float ql = qx[lane];
        float s = ql * ql;
        #pragma unroll
        for (int off = 32; off > 0; off >>= 1) s += __shfl_xor(s, off, 64);
        qn[q] = s;
    }

    // ---- causal scan bound, block-uniform (barriers inside loop!) ----
    // buckets < qb are guaranteed causal; bucket qb mixed -> scan through it.
    // If guaranteed-causal count < K, inf-fill needs smallest global idx ->
    // full scan (exact).
    int vmax = 0;
    #pragma unroll
    for (int q = 0; q < QPW; ++q) {
        const int qb = tbucket(qtv[q]);
        int bound = pf[qb + 1];
        if (pf[qb] < kK) bound = kNC;
        vmax = bound > vmax ? bound : vmax;
    }
    if (lane == 0) wred[w] = vmax;
    __syncthreads();
    int bmax = wred[0];
    #pragma unroll
    for (int i = 1; i < WAVES; ++i) bmax = wred[i] > bmax ? wred[i] : bmax;

    const int lo = h * HALF;
    const int hi = bmax < lo + HALF ? bmax : lo + HALF;
    const int ntile = (hi > lo) ? ((hi - lo + TILE - 1) >> 6) : 0;
    const size_t hbase = (size_t)lo * 16;        // float4 offset of this half

    // staging geometry: 4 float4 per thread per tile, XOR-swizzled LDS dest
    // (identical to validated v6 linear scheme -> coalesced, no gather)
    int sg[4], ss[4];
    #pragma unroll
    for (int i = 0; i < 4; ++i) {
        const int n = tid + 256 * i;
        const int r = n >> 4, j = n & 15;
        sg[i] = n;
        ss[i] = (r << 4) | (j ^ (r & 7));
    }
    if (ntile > 0) {
        #pragma unroll
        for (int i = 0; i < 4; ++i) xt[0][ss[i]] = xp4[hbase + sg[i]];
    }
    __syncthreads();

    const int lbase = lane << 4, lsw = lane & 7;
    const float INF = __builtin_inff();
    unsigned long long lst01 = ~0ull, lst23 = ~0ull;

    for (int t = 0; t < ntile; ++t) {
        float4 p0, p1, p2, p3;
        const bool pre = (t + 1 < ntile);
        if (pre) {
            const size_t nb = hbase + (size_t)(t + 1) * 1024;
            p0 = xp4[nb + sg[0]]; p1 = xp4[nb + sg[1]];
            p2 = xp4[nb + sg[2]]; p3 = xp4[nb + sg[3]];
        }
        const float4* buf = xt[t & 1];

        float dot[QPW] = {0.f, 0.f, 0.f, 0.f};
        #pragma unroll
        for (int j = 0; j < 16; ++j) {
            const float4 rv = buf[lbase | (j ^ lsw)];
            #pragma unroll
            for (int q = 0; q < QPW; ++q) {
                const float4 qv = ((const float4*)qxp[q])[j];   // s_load (uniform)
                dot[q] = fmaf(qv.x, rv.x, dot[q]);
                dot[q] = fmaf(qv.y, rv.y, dot[q]);
                dot[q] = fmaf(qv.z, rv.z, dot[q]);
                dot[q] = fmaf(qv.w, rv.w, dot[q]);
            }
        }

        // contiguous permuted metadata (no gather)
        const int pos = lo + t * TILE + lane;
        const float4 ms = msrt[pos];
        const int2   mr = mrn[pos];
        const float rs0 = ms.x, rs1 = ms.y, rs2 = ms.z, rtv = ms.w;
        const float rn  = __int_as_float(mr.x);     // +inf if masked-out
        const int   o   = mr.y;                      // original ref index (key!)
        const float rsn = rs0*rs0 + rs1*rs1 + rs2*rs2;

        #pragma unroll
        for (int q = 0; q < QPW; ++q) {
            float d_x = qn[q] + rn - 2.0f * dot[q];
            const float sdot = qs0[q]*rs0 + qs1[q]*rs1 + qs2[q]*rs2;
            float d_s = qsn[q] + rsn - 2.0f * sdot;
            float d_t = rtv - qtv[q];
            if (!(d_t <= 0.f)) d_t = INF;
            const float v = d_x*d_x + d_s*d_s + d_t*d_t;
            const unsigned long long key =
                ((unsigned long long)__float_as_uint(v) << 32) | (unsigned)o;
            if (q < 2) insert_half(lst01, key, lane, (q & 1) * 32);
            else       insert_half(lst23, key, lane, (q & 1) * 32);
        }

        if (pre) {
            float4* nbuf = xt[(t + 1) & 1];
            nbuf[ss[0]] = p0; nbuf[ss[1]] = p1;
            nbuf[ss[2]] = p2; nbuf[ss[3]] = p3;
        }
        __syncthreads();
    }

    // ---- write per-half sorted key lists: keys[gid][h][slot] ----
    #pragma unroll
    for (int p = 0; p < 2; ++p) {
        const unsigned long long key = p ? lst23 : lst01;
        const int gsel = (lane < 32) ? gid_q[2*p] : gid_q[2*p+1];
        keys[((size_t)gsel * 2 + h) * 32 + (lane & 31)] = key;
    }
}

// ---- merge two sorted 32-lists per query + validated emit (validated r7-r13) ----
__global__ __launch_bounds__(256)
void knn_v5_merge(const float* __restrict__ x_ctx, const float* __restrict__ s_ctx,
                  const float* __restrict__ t_ctx, const unsigned char* __restrict__ mask_ctx,
                  const float* __restrict__ x_test, const float* __restrict__ s_test,
                  const float* __restrict__ t_test,
                  const unsigned long long* __restrict__ keys,
                  float* __restrict__ out)
{
    __shared__ unsigned long long kbuf[WAVES][64];
    __shared__ unsigned long long merged[WAVES][32];

    const int tid  = threadIdx.x;
    const int lane = tid & 63;
    const int w    = tid >> 6;
    const int qid  = blockIdx.x * WAVES + w;

    int b; const float *qx, *qs, *qt;
    resolve_q(qid, x_ctx, s_ctx, t_ctx, x_test, s_test, t_test, b, qx, qs, qt);
    const float qs0_ = qs[0], qs1_ = qs[1], qs2_ = qs[2], qtv_ = qt[0];
    const float qsn_ = qs0_*qs0_ + qs1_*qs1_ + qs2_*qs2_;
    const float ql = qx[lane];
    float qn_ = ql * ql;
    #pragma unroll
    for (int off = 32; off > 0; off >>= 1) qn_ += __shfl_xor(qn_, off, 64);

    const unsigned long long mykey = keys[(size_t)qid * 64 + lane];
    kbuf[w][lane] = mykey;
    __syncthreads();

    int cnt = 0;
    const int ob = (lane < 32) ? 32 : 0;
    #pragma unroll
    for (int j = 0; j < 32; ++j) cnt += (kbuf[w][ob + j] < mykey) ? 1 : 0;
    const int pos = (lane & 31) + cnt;
    if (pos < 32) merged[w][pos] = mykey;
    __syncthreads();

    if (lane < kK) {
        const unsigned long long key = merged[w][lane];
        const int rsel = (int)(key & 0xFFFFFFFFull);

        const float*  rsp = s_ctx + (size_t)b * kNC * 3;
        const float*  rtp = t_ctx + (size_t)b * kNC;
        const unsigned char* mp = mask_ctx + (size_t)b * kNC;

        const float4* xr = (const float4*)(x_ctx + ((size_t)b * kNC + rsel) * kDX);
        const float4* qr = (const float4*)qx;
        float dot = 0.f, rn2 = 0.f;
        #pragma unroll
        for (int j = 0; j < 16; ++j) {
            const float4 rv = xr[j];
            const float4 qv = qr[j];
            rn2 = fmaf(rv.x, rv.x, rn2); rn2 = fmaf(rv.y, rv.y, rn2);
            rn2 = fmaf(rv.z, rv.z, rn2); rn2 = fmaf(rv.w, rv.w, rn2);
            dot = fmaf(qv.x, rv.x, dot); dot = fmaf(qv.y, rv.y, dot);
            dot = fmaf(qv.z, rv.z, dot); dot = fmaf(qv.w, rv.w, dot);
        }
        float d_x = qn_ + rn2 - 2.0f * dot;
        const float rs0 = rsp[rsel*3+0], rs1 = rsp[rsel*3+1], rs2 = rsp[rsel*3+2];
        const float rsn = rs0*rs0 + rs1*rs1 + rs2*rs2;
        const float sdot = qs0_*rs0 + qs1_*rs1 + qs2_*rs2;
        float d_s = qsn_ + rsn - 2.0f * sdot;
        const float dt_raw = rtp[rsel] - qtv_;
        const bool  m = (mp[rsel] != 0);
        const bool  causal = m && (dt_raw <= 0.f);

        const float em = causal ? 1.0f : 0.0f;
        const float d_x_out = m ? d_x : kBigFinite;
        const float d_s_out = m ? d_s : kBigFinite;
        const float d_t_out = causal ? dt_raw : kBigFinite;

        const size_t e = (size_t)qid * kK + (size_t)lane;
        out[e]                = (float)(rsel + b * kNC);
        out[(size_t)kE   + e] = (float)qid;
        out[(size_t)kE*2 + e] = d_x_out;
        out[(size_t)kE*3 + e] = d_s_out;
        out[(size_t)kE*4 + e] = d_t_out;
        out[(size_t)kE*5 + e] = em;
    }
}

// ================= fallback: validated round-6 kernel (v4) =================
__global__ __launch_bounds__(256, 4)
void knn_v4(const float* __restrict__ x_ctx, const float* __restrict__ s_ctx,
            const float* __restrict__ t_ctx, const unsigned char* __restrict__ mask_ctx,
            const float* __restrict__ x_test, const float* __restrict__ s_test,
            const float* __restrict__ t_test, float* __restrict__ out)
{
    __shared__ float4 xt[2][TILE * 16];
    const int tid  = threadIdx.x;
    const int lane = tid & 63;
    const int w    = __builtin_amdgcn_readfirstlane(tid >> 6);
    const int qbase = blockIdx.x * QPB;
    const int gid0  = qbase + w * QPW;
    int b;
    { int b_; const float *a, *c, *d;
      resolve_q(qbase, x_ctx, s_ctx, t_ctx, x_test, s_test, t_test, b_, a, c, d);
      b = b_; }
    const float4* xb4 = (const float4*)x_ctx + (size_t)b * kNC * (kDX / 4);
    const float*  rsp = s_ctx + (size_t)b * kNC * 3;
    const float*  rtp = t_ctx + (size_t)b * kNC;
    const unsigned char* mp = mask_ctx + (size_t)b * kNC;
    const float* qxp[QPW];
    float qs0[QPW], qs1[QPW], qs2[QPW], qsn[QPW], qtv[QPW], qn[QPW];
    #pragma unroll
    for (int q = 0; q < QPW; ++q) {
        int bb; const float *qx, *qs, *qt;
        resolve_q(gid0 + q, x_ctx, s_ctx, t_ctx, x_test, s_test, t_test, bb, qx, qs, qt);
        qxp[q] = qx;
        qs0[q] = qs[0]; qs1[q] = qs[1]; qs2[q] = qs[2]; qtv[q] = qt[0];
        qsn[q] = qs0[q]*qs0[q] + qs1[q]*qs1[q] + qs2[q]*qs2[q];
        const float ql = qx[lane];
        float s = ql * ql;
        #pragma unroll
        for (int off = 32; off > 0; off >>= 1) s += __shfl_xor(s, off, 64);
        qn[q] = s;
    }
    int sg[4], ss[4];
    #pragma unroll
    for (int i = 0; i < 4; ++i) {
        const int n = tid + 256 * i;
        const int r = n >> 4, j = n & 15;
        sg[i] = n; ss[i] = (r << 4) | (j ^ (r & 7));
    }
    #pragma unroll
    for (int i = 0; i < 4; ++i) xt[0][ss[i]] = xb4[sg[i]];
    __syncthreads();
    const int lbase = lane << 4, lsw = lane & 7;
    const float INF = __builtin_inff();
    unsigned long long lst01 = ~0ull, lst23 = ~0ull;
    for (int t = 0; t < kNC / TILE; ++t) {
        float4 p0, p1, p2, p3;
        const bool pre = (t + 1 < kNC / TILE);
        if (pre) {
            const size_t nb = (size_t)(t + 1) * 1024;
            p0 = xb4[nb + sg[0]]; p1 = xb4[nb + sg[1]];
            p2 = xb4[nb + sg[2]]; p3 = xb4[nb + sg[3]];
        }
        const float4* buf = xt[t & 1];
        float dot[QPW] = {0.f, 0.f, 0.f, 0.f};
        float rn = 0.f;
        #pragma unroll
        for (int j = 0; j < 16; ++j) {
            const float4 rv = buf[lbase | (j ^ lsw)];
            rn = fmaf(rv.x, rv.x, rn); rn = fmaf(rv.y, rv.y, rn);
            rn = fmaf(rv.z, rv.z, rn); rn = fmaf(rv.w, rv.w, rn);
            #pragma unroll
            for (int q = 0; q < QPW; ++q) {
                const float4 qv = ((const float4*)qxp[q])[j];
                dot[q] = fmaf(qv.x, rv.x, dot[q]);
                dot[q] = fmaf(qv.y, rv.y, dot[q]);
                dot[q] = fmaf(qv.z, rv.z, dot[q]);
                dot[q] = fmaf(qv.w, rv.w, dot[q]);
            }
        }
        const int r = t * TILE + lane;
        const float rs0 = rsp[r*3+0], rs1 = rsp[r*3+1], rs2 = rsp[r*3+2];
        const float rtv = rtp[r];
        const bool  m   = (mp[r] != 0);
        const float rsn = rs0*rs0 + rs1*rs1 + rs2*rs2;
        #pragma unroll
        for (int q = 0; q < QPW; ++q) {
            float d_x = qn[q] + rn - 2.0f * dot[q];
            const float sdot = qs0[q]*rs0 + qs1[q]*rs1 + qs2[q]*rs2;
            float d_s = qsn[q] + rsn - 2.0f * sdot;
            float d_t = rtv - qtv[q];
            if (!m) { d_x = INF; d_s = INF; d_t = INF; }
            if (!(d_t <= 0.f)) d_t = INF;
            const float v = d_x*d_x + d_s*d_s + d_t*d_t;
            const unsigned long long key =
                ((unsigned long long)__float_as_uint(v) << 32) | (unsigned)r;
            if (q < 2) insert_half(lst01, key, lane, (q & 1) * 32);
            else       insert_half(lst23, key, lane, (q & 1) * 32);
        }
        if (pre) {
            float4* nbuf = xt[(t + 1) & 1];
            nbuf[ss[0]] = p0; nbuf[ss[1]] = p1;
            nbuf[ss[2]] = p2; nbuf[ss[3]] = p3;
        }
        __syncthreads();
    }
    #pragma unroll
    for (int p = 0; p < 2; ++p) {
        const unsigned long long myl = p ? lst23 : lst01;
        const int qidx = 2 * p + (lane >> 5);
        const int rsel = (int)(myl & 0xFFFFFFFFull);
        const int gid  = gid0 + qidx;
        const float* qx  = (lane < 32) ? qxp[2*p] : qxp[2*p+1];
        const float qn_  = (lane < 32) ? qn [2*p] : qn [2*p+1];
        const float qs0_ = (lane < 32) ? qs0[2*p] : qs0[2*p+1];
        const float qs1_ = (lane < 32) ? qs1[2*p] : qs1[2*p+1];
        const float qs2_ = (lane < 32) ? qs2[2*p] : qs2[2*p+1];
        const float qsn_ = (lane < 32) ? qsn[2*p] : qsn[2*p+1];
        const float qtv_ = (lane < 32) ? qtv[2*p] : qtv[2*p+1];
        const float4* xr = (const float4*)(x_ctx + ((size_t)b * kNC + rsel) * kDX);
        const float4* qr = (const float4*)qx;
        float dot = 0.f, rn2 = 0.f;
        #pragma unroll
        for (int j = 0; j < 16; ++j) {
            const float4 rv = xr[j];
            const float4 qv = qr[j];
            rn2 = fmaf(rv.x, rv.x, rn2); rn2 = fmaf(rv.y, rv.y, rn2);
            rn2 = fmaf(rv.z, rv.z, rn2); rn2 = fmaf(rv.w, rv.w, rn2);
            dot = fmaf(qv.x, rv.x, dot); dot = fmaf(qv.y, rv.y, dot);
            dot = fmaf(qv.z, rv.z, dot); dot = fmaf(qv.w, rv.w, dot);
        }
        float d_x = qn_ + rn2 - 2.0f * dot;
        const float rs0 = rsp[rsel*3+0], rs1 = rsp[rsel*3+1], rs2 = rsp[rsel*3+2];
        const float rsn = rs0*rs0 + rs1*rs1 + rs2*rs2;
        const float sdot = qs0_*rs0 + qs1_*rs1 + qs2_*rs2;
        float d_s = qsn_ + rsn - 2.0f * sdot;
        const float dt_raw = rtp[rsel] - qtv_;
        const bool  m = (mp[rsel] != 0);
        const bool  causal = m && (dt_raw <= 0.f);
        const float em = causal ? 1.0f : 0.0f;
        const size_t e = (size_t)gid * kK + (size_t)(lane & 31);
        out[e]                = (float)(rsel + b * kNC);
        out[(size_t)kE   + e] = (float)gid;
        out[(size_t)kE*2 + e] = m ? d_x : kBigFinite;
        out[(size_t)kE*3 + e] = m ? d_s : kBigFinite;
        out[(size_t)kE*4 + e] = causal ? dt_raw : kBigFinite;
        out[(size_t)kE*5 + e] = em;
    }
}

extern "C" void kernel_launch(void* const* d_in, const int* in_sizes, int n_in,
                              void* d_out, int out_size, void* d_ws, size_t ws_size,
                              hipStream_t stream) {
    (void)in_sizes; (void)n_in; (void)out_size;
    const float* x_ctx = (const float*)d_in[0];
    const float* s_ctx = (const float*)d_in[1];
    const float* t_ctx = (const float*)d_in[2];
    const unsigned char* mask_ctx = (const unsigned char*)d_in[3];
    const float* x_test = (const float*)d_in[4];
    const float* s_test = (const float*)d_in[5];
    const float* t_test = (const float*)d_in[6];

    if (ws_size >= kWsNeed) {
        char* ws = (char*)d_ws;
        float* rn_ws = (float*)(ws + kOffRn);
        int*   permR = (int*)(ws + kOffPermR);
        int*   prefR = (int*)(ws + kOffPrefR);
        int*   cntR  = (int*)(ws + kOffCntR);
        int*   prefQ = (int*)(ws + kOffPrefQ);
        int*   cntQ  = (int*)(ws + kOffCntQ);
        int*   qperm = (int*)(ws + kOffQperm);
        unsigned long long* keys = (unsigned long long*)(ws + kOffKeys);
        float4* xp4  = (float4*)(ws + kOffXp);
        float4* msrt = (float4*)(ws + kOffMs);
        int2*   mrn  = (int2*)(ws + kOffMr);

        prep_zero   <<<dim3(4),   dim3(256), 0, stream>>>(cntR, cntQ);
        prep_rn     <<<dim3(32),  dim3(256), 0, stream>>>(x_ctx, rn_ws);
        prep_hist   <<<dim3(72),  dim3(256), 0, stream>>>(t_ctx, t_test, cntR, cntQ);
        prep_prefix <<<dim3(4),   dim3(256), 0, stream>>>(cntR, cntQ, prefR, prefQ);
        prep_scatter<<<dim3(72),  dim3(256), 0, stream>>>(t_ctx, t_test, cntR, cntQ,
                                                          permR, qperm);
        prep_permute<<<dim3(512), dim3(256), 0, stream>>>(x_ctx, s_ctx, t_ctx,
                                                          mask_ctx, rn_ws, permR,
                                                          xp4, msrt, mrn);
        knn_v8_part <<<dim3(2 * NGRP), dim3(256), 0, stream>>>(
            x_ctx, s_ctx, t_ctx, x_test, s_test, t_test,
            xp4, msrt, mrn, prefR, qperm, keys);
        knn_v5_merge<<<dim3(kNQ / WAVES), dim3(256), 0, stream>>>(
            x_ctx, s_ctx, t_ctx, mask_ctx, x_test, s_test, t_test, keys,
            (float*)d_out);
    } else {
        knn_v4<<<dim3(kNQ / QPB), dim3(256), 0, stream>>>(
            x_ctx, s_ctx, t_ctx, mask_ctx, x_test, s_test, t_test, (float*)d_out);
    }
}

// Round 15
// 359.858 us; speedup vs baseline: 1.4653x; 1.1833x over previous
//
#include <hip/hip_runtime.h>

namespace {
constexpr int kB  = 2;
constexpr int kNC = 4096;
constexpr int kNT = 1024;
constexpr int kDX = 64;
constexpr int kK  = 32;
constexpr int kNQ = kB * (kNC + kNT);            // 10240
constexpr int kQPB2 = kNC + kNT;                 // 5120 queries per batch
constexpr long long kE = (long long)kNQ * kK;    // 327680
constexpr int QPW  = 4;                          // queries per wave
constexpr int WAVES = 4;                         // waves per block
constexpr int QPB  = WAVES * QPW;                // 16 queries per block
constexpr int TILE = 64;                         // refs per LDS tile
constexpr int NGRP = kNQ / QPB;                  // 640 query groups
constexpr int GPB  = NGRP / kB;                  // 320 groups per batch
// inf stand-in: must stay finite after bf16 round-trip (FLT_MAX -> bf16 inf)
constexpr float kBigFinite = 1e30f;
// ---- ws layout (bytes) ----
constexpr size_t kOffRn    = 0;                       // f32 [8192]
constexpr size_t kOffPermR = 32768;                   // int [2][4096]
constexpr size_t kOffPrefR = 65536;                   // int [2][257] (+pad)
constexpr size_t kOffCntR  = 67840;                   // int [2][256]
constexpr size_t kOffPrefV = 69888;                   // int [2][257] valid-only (+pad)
constexpr size_t kOffCntV  = 72192;                   // int [2][256]
constexpr size_t kOffPrefQ = 74240;                   // int [2][257] (+pad)
constexpr size_t kOffCntQ  = 76544;                   // int [2][256]
constexpr size_t kOffQperm = 78592;                   // int [2][5120]
constexpr size_t kOffXp    = 119552;                  // f32 [2][4096][64] permuted x
constexpr size_t kOffMs    = 8508160;                 // f32x4 [2][4096] (rs0,rs1,rs2,rt)
constexpr size_t kOffMr    = 8639232;                 // int2 [2][4096]  (rn_bits, orig_idx)
constexpr size_t kWsNeed   = 8704768;                 // ~8.7MB
}

__device__ __forceinline__ int tbucket(float t) {
    int b = (int)(t * 256.0f);
    return b < 0 ? 0 : (b > 255 ? 255 : b);
}

__device__ __forceinline__ void resolve_q(int gid,
    const float* x_ctx, const float* s_ctx, const float* t_ctx,
    const float* x_test, const float* s_test, const float* t_test,
    int& b, const float*& qx, const float*& qs, const float*& qt)
{
    if (gid < kB * kNC) {
        b  = gid >> 12;
        qx = x_ctx + (size_t)gid * kDX;
        qs = s_ctx + (size_t)gid * 3;
        qt = t_ctx + gid;
    } else {
        const int g2 = gid - kB * kNC;
        b  = g2 >> 10;
        qx = x_test + (size_t)g2 * kDX;
        qs = s_test + (size_t)g2 * 3;
        qt = t_test + g2;
    }
}

// Exact online insert into wave-held sorted ascending top-32 (validated r4-r14).
__device__ __forceinline__ void insert_half(unsigned long long& listKey,
    unsigned long long keyQ, int lane, int base)
{
    const unsigned long long thr = __shfl(listKey, base + 31, 64);
    unsigned long long hb = __ballot(keyQ < thr);
    while (hb) {
        const int srcl = __ffsll((unsigned long long)hb) - 1;
        hb &= hb - 1;
        const unsigned long long K = __shfl(keyQ, srcl, 64);
        const unsigned long long lt = __ballot(listKey < K);
        const unsigned int half = base ? (unsigned int)(lt >> 32)
                                       : (unsigned int)lt;
        const int pos = __popc(half) + base;
        if (pos < base + 32) {
            const unsigned long long up = __shfl_up(listKey, 1, 64);
            if (lane >= base && lane < base + 32) {
                if (lane > pos)       listKey = up;
                else if (lane == pos) listKey = K;
            }
        }
    }
}

// ---- prep: rn[row] with the exact validated fmaf chain (validated r5-r14) ----
__global__ __launch_bounds__(256)
void prep_rn(const float* __restrict__ x, float* __restrict__ rn_ws)
{
    const int r = blockIdx.x * 256 + threadIdx.x;    // 0..8191
    const float4* xr = (const float4*)(x + (size_t)r * kDX);
    float rn = 0.f;
    #pragma unroll
    for (int j = 0; j < 16; ++j) {
        const float4 rv = xr[j];
        rn = fmaf(rv.x, rv.x, rn); rn = fmaf(rv.y, rv.y, rn);
        rn = fmaf(rv.z, rv.z, rn); rn = fmaf(rv.w, rv.w, rn);
    }
    rn_ws[r] = rn;
}

// ---- prep: zero histogram counters (R, V, Q) ----
__global__ __launch_bounds__(256)
void prep_zero(int* __restrict__ cntR, int* __restrict__ cntV,
               int* __restrict__ cntQ)
{
    const int i = blockIdx.x * 256 + threadIdx.x;    // grid 6 -> 1536
    if (i < 512)       cntR[i] = 0;
    else if (i < 1024) cntV[i - 512] = 0;
    else               cntQ[i - 1024] = 0;
}

// ---- prep: histogram refs (pos + valid-only) and queries into 256 buckets ----
__global__ __launch_bounds__(256)
void prep_hist(const float* __restrict__ t_ctx, const float* __restrict__ t_test,
               const unsigned char* __restrict__ mask_ctx,
               int* __restrict__ cntR, int* __restrict__ cntV,
               int* __restrict__ cntQ)
{
    const int i = blockIdx.x * 256 + threadIdx.x;    // grid 72 -> 18432
    if (i < 8192) {
        const int b = i >> 12;
        const int bkt = tbucket(t_ctx[i]);
        atomicAdd(&cntR[b * 256 + bkt], 1);
        if (mask_ctx[i] != 0) atomicAdd(&cntV[b * 256 + bkt], 1);
    } else {
        const int gid = i - 8192;
        const int b = (gid < kB * kNC) ? (gid >> 12) : ((gid - kB * kNC) >> 10);
        const float qt = (gid < kB * kNC) ? t_ctx[gid] : t_test[gid - kB * kNC];
        atomicAdd(&cntQ[b * 256 + tbucket(qt)], 1);
    }
}

// ---- prep: exclusive prefix over 256 buckets; reset cnt to offsets ----
__global__ __launch_bounds__(256)
void prep_prefix(int* __restrict__ cntR, int* __restrict__ cntV,
                 int* __restrict__ cntQ,
                 int* __restrict__ prefR, int* __restrict__ prefV,
                 int* __restrict__ prefQ)
{
    __shared__ int sh[256];
    const int blk = blockIdx.x;   // 0,1 R; 2,3 V; 4,5 Q
    int* cnt  = (blk < 2) ? (cntR  + blk * 256)
              : (blk < 4) ? (cntV  + (blk - 2) * 256)
                          : (cntQ  + (blk - 4) * 256);
    int* pref = (blk < 2) ? (prefR + blk * 257)
              : (blk < 4) ? (prefV + (blk - 2) * 257)
                          : (prefQ + (blk - 4) * 257);
    const int tid = threadIdx.x;
    sh[tid] = cnt[tid];
    __syncthreads();
    if (tid == 0) {
        int acc = 0;
        for (int i = 0; i < 256; ++i) { const int v = sh[i]; sh[i] = acc; acc += v; }
        pref[256] = acc;
    }
    __syncthreads();
    pref[tid] = sh[tid];
    cnt[tid]  = sh[tid];
}

// ---- prep: scatter refs/queries into bucket-sorted order ----
__global__ __launch_bounds__(256)
void prep_scatter(const float* __restrict__ t_ctx, const float* __restrict__ t_test,
                  int* __restrict__ cntR, int* __restrict__ cntQ,
                  int* __restrict__ permR, int* __restrict__ qperm)
{
    const int i = blockIdx.x * 256 + threadIdx.x;    // grid 72
    if (i < 8192) {
        const int b = i >> 12, rl = i & (kNC - 1);
        const int pos = atomicAdd(&cntR[b * 256 + tbucket(t_ctx[i])], 1);
        permR[b * kNC + pos] = rl;
    } else {
        const int gid = i - 8192;
        const int b = (gid < kB * kNC) ? (gid >> 12) : ((gid - kB * kNC) >> 10);
        const float qt = (gid < kB * kNC) ? t_ctx[gid] : t_test[gid - kB * kNC];
        const int pos = atomicAdd(&cntQ[b * 256 + tbucket(qt)], 1);
        qperm[b * kQPB2 + pos] = gid;
    }
}

// ---- prep: physically permute x panel + metadata into rt-sorted order ----
// (validated r14: kills the hot-loop gather that sank v7)
__global__ __launch_bounds__(256)
void prep_permute(const float* __restrict__ x_ctx, const float* __restrict__ s_ctx,
                  const float* __restrict__ t_ctx, const unsigned char* __restrict__ mask_ctx,
                  const float* __restrict__ rn_ws, const int* __restrict__ permR,
                  float4* __restrict__ xp4, float4* __restrict__ msrt,
                  int2* __restrict__ mrn)
{
    const int n   = blockIdx.x * 256 + threadIdx.x;  // grid 512 -> 131072 float4
    const int b   = n >> 16;                          // 65536 float4 per batch
    const int rem = n & 65535;
    const int pos = rem >> 4, col = rem & 15;
    const int o   = permR[b * kNC + pos];
    xp4[n] = ((const float4*)x_ctx)[(size_t)b * kNC * 16 + (size_t)o * 16 + col];
    if (col == 0) {
        const float* rs = s_ctx + ((size_t)b * kNC + o) * 3;
        const float rtv = t_ctx[b * kNC + o];
        msrt[b * kNC + pos] = make_float4(rs[0], rs[1], rs[2], rtv);
        // mask folding: poison rn to +inf when masked-out -> v = +inf exactly
        const bool m = (mask_ctx[b * kNC + o] != 0);
        const float rn = rn_ws[b * kNC + o];
        mrn[b * kNC + pos] = make_int2(
            m ? __float_as_int(rn) : __float_as_int(__builtin_inff()), o);
    }
}

// ---- main: causal-pruned single-pass scan (no split-K) + direct emit ----
__global__ __launch_bounds__(256, 4)
void knn_v9(const float* __restrict__ x_ctx, const float* __restrict__ s_ctx,
            const float* __restrict__ t_ctx, const unsigned char* __restrict__ mask_ctx,
            const float* __restrict__ x_test, const float* __restrict__ s_test,
            const float* __restrict__ t_test,
            const float4* __restrict__ xp4g, const float4* __restrict__ msrtg,
            const int2* __restrict__ mrng,
            const int* __restrict__ prefR, const int* __restrict__ prefV,
            const int* __restrict__ qperm, float* __restrict__ out)
{
    __shared__ float4 xt[2][TILE * 16];   // 2 x 16KB double-buffered ref tiles

    const int tid  = threadIdx.x;
    const int lane = tid & 63;
    const int w    = __builtin_amdgcn_readfirstlane(tid >> 6);
    const int blk  = blockIdx.x;                 // 640
    const int b    = blk & 1;                    // interleave batches (LPT)
    const int gg   = (GPB - 1) - (blk >> 1);     // heavy (high-qt) groups first

    const int* qpm = qperm + b * kQPB2 + gg * QPB;
    int gid_q[QPW];
    #pragma unroll
    for (int q = 0; q < QPW; ++q) gid_q[q] = qpm[w * QPW + q];

    const float4* xp4  = xp4g  + (size_t)b * kNC * 16;
    const float4* msrt = msrtg + (size_t)b * kNC;
    const int2*   mrn  = mrng  + (size_t)b * kNC;
    const int*    pf   = prefR + b * 257;
    const int*    pfv  = prefV + b * 257;

    // ---- block-uniform causal scan bound over ALL 16 queries ----
    // (every thread computes it redundantly -> no LDS exchange, no barrier;
    //  identical result since inputs are block-uniform scalar loads)
    int bmax = 0;
    #pragma unroll
    for (int i = 0; i < QPB; ++i) {
        const int gq = qpm[i];
        const float qt = (gq < kB * kNC) ? t_ctx[gq] : t_test[gq - kB * kNC];
        const int qb = tbucket(qt);
        int bound = pf[qb + 1];
        if (pfv[qb] < kK) bound = kNC;   // <K guaranteed-causal VALID refs
        bmax = bound > bmax ? bound : bmax;
    }
    const int ntile = (bmax + TILE - 1) >> 6;    // >= 1 always

    // ---- per-wave query setup (4 queries; pointers wave-uniform) ----
    const float* qxp[QPW];
    float qs0[QPW], qs1[QPW], qs2[QPW], qsn[QPW], qtv[QPW], qn[QPW];
    #pragma unroll
    for (int q = 0; q < QPW; ++q) {
        int bb; const float *qx, *qs, *qt;
        resolve_q(gid_q[q], x_ctx, s_ctx, t_ctx, x_test, s_test, t_test,
                  bb, qx, qs, qt);
        qxp[q] = qx;
        qs0[q] = qs[0]; qs1[q] = qs[1]; qs2[q] = qs[2]; qtv[q] = qt[0];
        qsn[q] = qs0[q]*qs0[q] + qs1[q]*qs1[q] + qs2[q]*qs2[q];
        const float ql = qx[lane];
        float s = ql * ql;
        #pragma unroll
        for (int off = 32; off > 0; off >>= 1) s += __shfl_xor(s, off, 64);
        qn[q] = s;
    }

    // staging geometry: 4 float4 per thread per tile, XOR-swizzled LDS dest
    int sg[4], ss[4];
    #pragma unroll
    for (int i = 0; i < 4; ++i) {
        const int n = tid + 256 * i;
        const int r = n >> 4, j = n & 15;
        sg[i] = n;
        ss[i] = (r << 4) | (j ^ (r & 7));
    }
    #pragma unroll
    for (int i = 0; i < 4; ++i) xt[0][ss[i]] = xp4[sg[i]];
    __syncthreads();

    const int lbase = lane << 4, lsw = lane & 7;
    const float INF = __builtin_inff();
    unsigned long long lst01 = ~0ull, lst23 = ~0ull;

    for (int t = 0; t < ntile; ++t) {
        float4 p0, p1, p2, p3;
        const bool pre = (t + 1 < ntile);
        if (pre) {
            const size_t nb = (size_t)(t + 1) * 1024;
            p0 = xp4[nb + sg[0]]; p1 = xp4[nb + sg[1]];
            p2 = xp4[nb + sg[2]]; p3 = xp4[nb + sg[3]];
        }
        const float4* buf = xt[t & 1];

        float dot[QPW] = {0.f, 0.f, 0.f, 0.f};
        #pragma unroll
        for (int j = 0; j < 16; ++j) {
            const float4 rv = buf[lbase | (j ^ lsw)];
            #pragma unroll
            for (int q = 0; q < QPW; ++q) {
                const float4 qv = ((const float4*)qxp[q])[j];   // s_load (uniform)
                dot[q] = fmaf(qv.x, rv.x, dot[q]);
                dot[q] = fmaf(qv.y, rv.y, dot[q]);
                dot[q] = fmaf(qv.z, rv.z, dot[q]);
                dot[q] = fmaf(qv.w, rv.w, dot[q]);
            }
        }

        // contiguous permuted metadata (no gather; validated r14)
        const int pos = t * TILE + lane;
        const float4 ms = msrt[pos];
        const int2   mr = mrn[pos];
        const float rs0 = ms.x, rs1 = ms.y, rs2 = ms.z, rtv = ms.w;
        const float rn  = __int_as_float(mr.x);     // +inf if masked-out
        const int   o   = mr.y;                      // original ref index (key!)
        const float rsn = rs0*rs0 + rs1*rs1 + rs2*rs2;

        #pragma unroll
        for (int q = 0; q < QPW; ++q) {
            float d_x = qn[q] + rn - 2.0f * dot[q];
            const float sdot = qs0[q]*rs0 + qs1[q]*rs1 + qs2[q]*rs2;
            float d_s = qsn[q] + rsn - 2.0f * sdot;
            float d_t = rtv - qtv[q];
            if (!(d_t <= 0.f)) d_t = INF;
            const float v = d_x*d_x + d_s*d_s + d_t*d_t;
            const unsigned long long key =
                ((unsigned long long)__float_as_uint(v) << 32) | (unsigned)o;
            if (q < 2) insert_half(lst01, key, lane, (q & 1) * 32);
            else       insert_half(lst23, key, lane, (q & 1) * 32);
        }

        if (pre) {
            float4* nbuf = xt[(t + 1) & 1];
            nbuf[ss[0]] = p0; nbuf[ss[1]] = p1;
            nbuf[ss[2]] = p2; nbuf[ss[3]] = p3;
        }
        __syncthreads();
    }

    // ---- emit: 2 passes, 64 lanes each (validated v4 epilogue) ----
    const float*  rsp = s_ctx + (size_t)b * kNC * 3;
    const float*  rtp = t_ctx + (size_t)b * kNC;
    const unsigned char* mp = mask_ctx + (size_t)b * kNC;
    #pragma unroll
    for (int p = 0; p < 2; ++p) {
        const unsigned long long myl = p ? lst23 : lst01;
        const int qidx = 2 * p + (lane >> 5);
        const int rsel = (int)(myl & 0xFFFFFFFFull);
        const int gid  = gid_q[qidx];
        const float* qx  = (lane < 32) ? qxp[2*p] : qxp[2*p+1];
        const float qn_  = (lane < 32) ? qn [2*p] : qn [2*p+1];
        const float qs0_ = (lane < 32) ? qs0[2*p] : qs0[2*p+1];
        const float qs1_ = (lane < 32) ? qs1[2*p] : qs1[2*p+1];
        const float qs2_ = (lane < 32) ? qs2[2*p] : qs2[2*p+1];
        const float qsn_ = (lane < 32) ? qsn[2*p] : qsn[2*p+1];
        const float qtv_ = (lane < 32) ? qtv[2*p] : qtv[2*p+1];

        const float4* xr = (const float4*)(x_ctx + ((size_t)b * kNC + rsel) * kDX);
        const float4* qr = (const float4*)qx;
        float dot = 0.f, rn2 = 0.f;
        #pragma unroll
        for (int j = 0; j < 16; ++j) {
            const float4 rv = xr[j];
            const float4 qv = qr[j];
            rn2 = fmaf(rv.x, rv.x, rn2); rn2 = fmaf(rv.y, rv.y, rn2);
            rn2 = fmaf(rv.z, rv.z, rn2); rn2 = fmaf(rv.w, rv.w, rn2);
            dot = fmaf(qv.x, rv.x, dot); dot = fmaf(qv.y, rv.y, dot);
            dot = fmaf(qv.z, rv.z, dot); dot = fmaf(qv.w, rv.w, dot);
        }
        float d_x = qn_ + rn2 - 2.0f * dot;
        const float rs0 = rsp[rsel*3+0], rs1 = rsp[rsel*3+1], rs2 = rsp[rsel*3+2];
        const float rsn = rs0*rs0 + rs1*rs1 + rs2*rs2;
        const float sdot = qs0_*rs0 + qs1_*rs1 + qs2_*rs2;
        float d_s = qsn_ + rsn - 2.0f * sdot;
        const float dt_raw = rtp[rsel] - qtv_;
        const bool  m = (mp[rsel] != 0);
        const bool  causal = m && (dt_raw <= 0.f);

        const float em = causal ? 1.0f : 0.0f;
        const float d_x_out = m ? d_x : kBigFinite;
        const float d_s_out = m ? d_s : kBigFinite;
        const float d_t_out = causal ? dt_raw : kBigFinite;

        const size_t e = (size_t)gid * kK + (size_t)(lane & 31);
        out[e]                = (float)(rsel + b * kNC);
        out[(size_t)kE   + e] = (float)gid;
        out[(size_t)kE*2 + e] = d_x_out;
        out[(size_t)kE*3 + e] = d_s_out;
        out[(size_t)kE*4 + e] = d_t_out;
        out[(size_t)kE*5 + e] = em;
    }
}

// ================= fallback: validated round-6 kernel (v4) =================
__global__ __launch_bounds__(256, 4)
void knn_v4(const float* __restrict__ x_ctx, const float* __restrict__ s_ctx,
            const float* __restrict__ t_ctx, const unsigned char* __restrict__ mask_ctx,
            const float* __restrict__ x_test, const float* __restrict__ s_test,
            const float* __restrict__ t_test, float* __restrict__ out)
{
    __shared__ float4 xt[2][TILE * 16];
    const int tid  = threadIdx.x;
    const int lane = tid & 63;
    const int w    = __builtin_amdgcn_readfirstlane(tid >> 6);
    const int qbase = blockIdx.x * QPB;
    const int gid0  = qbase + w * QPW;
    int b;
    { int b_; const float *a, *c, *d;
      resolve_q(qbase, x_ctx, s_ctx, t_ctx, x_test, s_test, t_test, b_, a, c, d);
      b = b_; }
    const float4* xb4 = (const float4*)x_ctx + (size_t)b * kNC * (kDX / 4);
    const float*  rsp = s_ctx + (size_t)b * kNC * 3;
    const float*  rtp = t_ctx + (size_t)b * kNC;
    const unsigned char* mp = mask_ctx + (size_t)b * kNC;
    const float* qxp[QPW];
    float qs0[QPW], qs1[QPW], qs2[QPW], qsn[QPW], qtv[QPW], qn[QPW];
    #pragma unroll
    for (int q = 0; q < QPW; ++q) {
        int bb; const float *qx, *qs, *qt;
        resolve_q(gid0 + q, x_ctx, s_ctx, t_ctx, x_test, s_test, t_test, bb, qx, qs, qt);
        qxp[q] = qx;
        qs0[q] = qs[0]; qs1[q] = qs[1]; qs2[q] = qs[2]; qtv[q] = qt[0];
        qsn[q] = qs0[q]*qs0[q] + qs1[q]*qs1[q] + qs2[q]*qs2[q];
        const float ql = qx[lane];
        float s = ql * ql;
        #pragma unroll
        for (int off = 32; off > 0; off >>= 1) s += __shfl_xor(s, off, 64);
        qn[q] = s;
    }
    int sg[4], ss[4];
    #pragma unroll
    for (int i = 0; i < 4; ++i) {
        const int n = tid + 256 * i;
        const int r = n >> 4, j = n & 15;
        sg[i] = n; ss[i] = (r << 4) | (j ^ (r & 7));
    }
    #pragma unroll
    for (int i = 0; i < 4; ++i) xt[0][ss[i]] = xb4[sg[i]];
    __syncthreads();
    const int lbase = lane << 4, lsw = lane & 7;
    const float INF = __builtin_inff();
    unsigned long long lst01 = ~0ull, lst23 = ~0ull;
    for (int t = 0; t < kNC / TILE; ++t) {
        float4 p0, p1, p2, p3;
        const bool pre = (t + 1 < kNC / TILE);
        if (pre) {
            const size_t nb = (size_t)(t + 1) * 1024;
            p0 = xb4[nb + sg[0]]; p1 = xb4[nb + sg[1]];
            p2 = xb4[nb + sg[2]]; p3 = xb4[nb + sg[3]];
        }
        const float4* buf = xt[t & 1];
        float dot[QPW] = {0.f, 0.f, 0.f, 0.f};
        float rn = 0.f;
        #pragma unroll
        for (int j = 0; j < 16; ++j) {
            const float4 rv = buf[lbase | (j ^ lsw)];
            rn = fmaf(rv.x, rv.x, rn); rn = fmaf(rv.y, rv.y, rn);
            rn = fmaf(rv.z, rv.z, rn); rn = fmaf(rv.w, rv.w, rn);
            #pragma unroll
            for (int q = 0; q < QPW; ++q) {
                const float4 qv = ((const float4*)qxp[q])[j];
                dot[q] = fmaf(qv.x, rv.x, dot[q]);
                dot[q] = fmaf(qv.y, rv.y, dot[q]);
                dot[q] = fmaf(qv.z, rv.z, dot[q]);
                dot[q] = fmaf(qv.w, rv.w, dot[q]);
            }
        }
        const int r = t * TILE + lane;
        const float rs0 = rsp[r*3+0], rs1 = rsp[r*3+1], rs2 = rsp[r*3+2];
        const float rtv = rtp[r];
        const bool  m   = (mp[r] != 0);
        const float rsn = rs0*rs0 + rs1*rs1 + rs2*rs2;
        #pragma unroll
        for (int q = 0; q < QPW; ++q) {
            float d_x = qn[q] + rn - 2.0f * dot[q];
            const float sdot = qs0[q]*rs0 + qs1[q]*rs1 + qs2[q]*rs2;
            float d_s = qsn[q] + rsn - 2.0f * sdot;
            float d_t = rtv - qtv[q];
            if (!m) { d_x = INF; d_s = INF; d_t = INF; }
            if (!(d_t <= 0.f)) d_t = INF;
            const float v = d_x*d_x + d_s*d_s + d_t*d_t;
            const unsigned long long key =
                ((unsigned long long)__float_as_uint(v) << 32) | (unsigned)r;
            if (q < 2) insert_half(lst01, key, lane, (q & 1) * 32);
            else       insert_half(lst23, key, lane, (q & 1) * 32);
        }
        if (pre) {
            float4* nbuf = xt[(t + 1) & 1];
            nbuf[ss[0]] = p0; nbuf[ss[1]] = p1;
            nbuf[ss[2]] = p2; nbuf[ss[3]] = p3;
        }
        __syncthreads();
    }
    #pragma unroll
    for (int p = 0; p < 2; ++p) {
        const unsigned long long myl = p ? lst23 : lst01;
        const int qidx = 2 * p + (lane >> 5);
        const int rsel = (int)(myl & 0xFFFFFFFFull);
        const int gid  = gid0 + qidx;
        const float* qx  = (lane < 32) ? qxp[2*p] : qxp[2*p+1];
        const float qn_  = (lane < 32) ? qn [2*p] : qn [2*p+1];
        const float qs0_ = (lane < 32) ? qs0[2*p] : qs0[2*p+1];
        const float qs1_ = (lane < 32) ? qs1[2*p] : qs1[2*p+1];
        const float qs2_ = (lane < 32) ? qs2[2*p] : qs2[2*p+1];
        const float qsn_ = (lane < 32) ? qsn[2*p] : qsn[2*p+1];
        const float qtv_ = (lane < 32) ? qtv[2*p] : qtv[2*p+1];
        const float4* xr = (const float4*)(x_ctx + ((size_t)b * kNC + rsel) * kDX);
        const float4* qr = (const float4*)qx;
        float dot = 0.f, rn2 = 0.f;
        #pragma unroll
        for (int j = 0; j < 16; ++j) {
            const float4 rv = xr[j];
            const float4 qv = qr[j];
            rn2 = fmaf(rv.x, rv.x, rn2); rn2 = fmaf(rv.y, rv.y, rn2);
            rn2 = fmaf(rv.z, rv.z, rn2); rn2 = fmaf(rv.w, rv.w, rn2);
            dot = fmaf(qv.x, rv.x, dot); dot = fmaf(qv.y, rv.y, dot);
            dot = fmaf(qv.z, rv.z, dot); dot = fmaf(qv.w, rv.w, dot);
        }
        float d_x = qn_ + rn2 - 2.0f * dot;
        const float rs0 = rsp[rsel*3+0], rs1 = rsp[rsel*3+1], rs2 = rsp[rsel*3+2];
        const float rsn = rs0*rs0 + rs1*rs1 + rs2*rs2;
        const float sdot = qs0_*rs0 + qs1_*rs1 + qs2_*rs2;
        float d_s = qsn_ + rsn - 2.0f * sdot;
        const float dt_raw = rtp[rsel] - qtv_;
        const bool  m = (mp[rsel] != 0);
        const bool  causal = m && (dt_raw <= 0.f);
        const float em = causal ? 1.0f : 0.0f;
        const size_t e = (size_t)gid * kK + (size_t)(lane & 31);
        out[e]                = (float)(rsel + b * kNC);
        out[(size_t)kE   + e] = (float)gid;
        out[(size_t)kE*2 + e] = m ? d_x : kBigFinite;
        out[(size_t)kE*3 + e] = m ? d_s : kBigFinite;
        out[(size_t)kE*4 + e] = causal ? dt_raw : kBigFinite;
        out[(size_t)kE*5 + e] = em;
    }
}

extern "C" void kernel_launch(void* const* d_in, const int* in_sizes, int n_in,
                              void* d_out, int out_size, void* d_ws, size_t ws_size,
                              hipStream_t stream) {
    (void)in_sizes; (void)n_in; (void)out_size;
    const float* x_ctx = (const float*)d_in[0];
    const float* s_ctx = (const float*)d_in[1];
    const float* t_ctx = (const float*)d_in[2];
    const unsigned char* mask_ctx = (const unsigned char*)d_in[3];
    const float* x_test = (const float*)d_in[4];
    const float* s_test = (const float*)d_in[5];
    const float* t_test = (const float*)d_in[6];

    if (ws_size >= kWsNeed) {
        char* ws = (char*)d_ws;
        float* rn_ws = (float*)(ws + kOffRn);
        int*   permR = (int*)(ws + kOffPermR);
        int*   prefR = (int*)(ws + kOffPrefR);
        int*   cntR  = (int*)(ws + kOffCntR);
        int*   prefV = (int*)(ws + kOffPrefV);
        int*   cntV  = (int*)(ws + kOffCntV);
        int*   prefQ = (int*)(ws + kOffPrefQ);
        int*   cntQ  = (int*)(ws + kOffCntQ);
        int*   qperm = (int*)(ws + kOffQperm);
        float4* xp4  = (float4*)(ws + kOffXp);
        float4* msrt = (float4*)(ws + kOffMs);
        int2*   mrn  = (int2*)(ws + kOffMr);

        prep_zero   <<<dim3(6),   dim3(256), 0, stream>>>(cntR, cntV, cntQ);
        prep_rn     <<<dim3(32),  dim3(256), 0, stream>>>(x_ctx, rn_ws);
        prep_hist   <<<dim3(72),  dim3(256), 0, stream>>>(t_ctx, t_test, mask_ctx,
                                                          cntR, cntV, cntQ);
        prep_prefix <<<dim3(6),   dim3(256), 0, stream>>>(cntR, cntV, cntQ,
                                                          prefR, prefV, prefQ);
        prep_scatter<<<dim3(72),  dim3(256), 0, stream>>>(t_ctx, t_test, cntR, cntQ,
                                                          permR, qperm);
        prep_permute<<<dim3(512), dim3(256), 0, stream>>>(x_ctx, s_ctx, t_ctx,
                                                          mask_ctx, rn_ws, permR,
                                                          xp4, msrt, mrn);
        knn_v9      <<<dim3(NGRP), dim3(256), 0, stream>>>(
            x_ctx, s_ctx, t_ctx, mask_ctx, x_test, s_test, t_test,
            xp4, msrt, mrn, prefR, prefV, qperm, (float*)d_out);
    } else {
        knn_v4<<<dim3(kNQ / QPB), dim3(256), 0, stream>>>(
            x_ctx, s_ctx, t_ctx, mask_ctx, x_test, s_test, t_test, (float*)d_out);
    }
}